// Round 9
// baseline (386.161 us; speedup 1.0000x reference)
//
#include <hip/hip_runtime.h>
#include <hip/hip_bf16.h>

#define NN 3072
#define FIN 512
#define FOUT 256

typedef __attribute__((ext_vector_type(8))) short short8;
typedef __attribute__((ext_vector_type(4))) float f32x4;

__device__ __forceinline__ short f2bf(float f) {
  union { float f; unsigned u; } v; v.f = f;
  unsigned r = v.u + 0x7fffu + ((v.u >> 16) & 1u);  // RNE
  return (short)(r >> 16);
}

__device__ __forceinline__ void glds16(const short* g, short* l) {
  __builtin_amdgcn_global_load_lds(
      (const __attribute__((address_space(1))) unsigned*)g,
      (__attribute__((address_space(3))) unsigned*)l, 16, 0, 0);
}

template<int N> __device__ __forceinline__ void wait_vm() {
  if constexpr (N == 0)      asm volatile("s_waitcnt vmcnt(0)" ::: "memory");
  else if constexpr (N == 4) asm volatile("s_waitcnt vmcnt(4)" ::: "memory");
  else                       asm volatile("s_waitcnt vmcnt(8)" ::: "memory");
}

// ---------------- prep kernels (verified) ----------------

__global__ __launch_bounds__(256) void prep_adj(const float* __restrict__ adj,
    short* __restrict__ adjbf, float2* __restrict__ dinv, const float* __restrict__ hptr)
{
  int m = blockIdx.x;
  int tid = threadIdx.x;
  const float4* row = (const float4*)(adj + (size_t)m * NN);
  short4* obf = (short4*)(adjbf + (size_t)m * NN);
  float sum = 0.f;
#pragma unroll
  for (int i = 0; i < NN / 4 / 256; ++i) {
    int idx = i * 256 + tid;
    float4 v = row[idx];
    sum += (v.x + v.y) + (v.z + v.w);
    obf[idx] = make_short4(f2bf(v.x), f2bf(v.y), f2bf(v.z), f2bf(v.w));
  }
#pragma unroll
  for (int off = 32; off > 0; off >>= 1) sum += __shfl_down(sum, off, 64);
  __shared__ float red[4];
  if ((tid & 63) == 0) red[tid >> 6] = sum;
  __syncthreads();
  if (tid == 0) {
    float s = red[0] + red[1] + red[2] + red[3];
    float h = hptr[0];
    float r = h * (1.f - s);
    float den = r * r + 1.f;
    dinv[m] = make_float2(r / den, -1.f / den);
  }
}

// merged prep_x (blocks 0..1535) + prep_w (blocks 1536..4095)  [r8-verified]
__global__ __launch_bounds__(256) void prep_xw(const float* __restrict__ x,
    const float* __restrict__ w0, const float* __restrict__ wr,
    const float* __restrict__ wi, short* __restrict__ xbf, short* __restrict__ wpack)
{
  int b = blockIdx.x;
  if (b < 1536) {
    int idx = b * 256 + threadIdx.x;
    float4 v = ((const float4*)x)[idx];
    ((short4*)xbf)[idx] = make_short4(f2bf(v.x), f2bf(v.y), f2bf(v.z), f2bf(v.w));
  } else {
    int idx = (b - 1536) * 256 + threadIdx.x;   // [1280][512]
    int f = idx & 511;
    int i = idx >> 9;
    float v;
    if (i < 1024) {
      int j = (i < 512) ? 1 : 0;
      int local = i & 511;
      int c = local >> 1;
      const float* src = (local & 1) ? wi : wr;
      v = src[((size_t)j * FIN + f) * FOUT + c];
    } else {
      v = w0[(size_t)f * FOUT + (i - 1024)];
    }
    wpack[idx] = f2bf(v);
  }
}

// ---------------- 64x64-tile GEMM, TRIPLE-buffered, counted vmcnt ----------------
// R7 geometry exactly (4 waves 2x2 of 32x32, BK=64, XOR swizzle, XCD decode,
// 3 blocks/CU at 48KB LDS) with pipeline depth 2 -> 3: stages t+1 AND t+2 in
// flight during compute(t); 12 outstanding loads/wave. Single-variable A/B
// vs R7 (depth-2, 43.9us wide).
template<int MODE, int KTOT, int ITILES>
__global__ __launch_bounds__(256, 4) void gemm_t(
    const short* __restrict__ Apan, int lda,
    const short* __restrict__ Badj, int ldb,
    const float* __restrict__ Vin,
    const float* __restrict__ Yin,
    float* __restrict__ Fout,
    short* __restrict__ Bout,
    const float2* __restrict__ dinv,
    const float* __restrict__ hptr)
{
  constexpr int BK = 64;
  constexpr int NT = KTOT / BK;

  __shared__ short As[3][64 * BK];
  __shared__ short Bs[3][64 * BK];

  const int tid  = threadIdx.x;
  const int lane = tid & 63;
  const int w    = tid >> 6;
  const int l15  = lane & 15;
  const int wrow = w >> 1, wcol = w & 1;

  // XCD-clustered decode: 8 XCDs x 6 j-columns x ITILES
  const int bid = blockIdx.x;
  const int xcd = bid & 7;
  const int s   = bid >> 3;
  const int jt  = xcd * 6 + s / ITILES;
  const int it  = s % ITILES;

  const int i0 = it * 64;
  const int j0 = jt * 64;

  const int srow = lane >> 3;                 // 0..7
  const int scol = ((lane & 7) ^ srow) * 8;   // source chunk XOR-swizzle (r2/r5/r7)

  const short* aSrc = Apan + (size_t)i0 * lda;
  const short* bSrc = Badj + (size_t)j0 * ldb;

  auto STAGE = [&](int t, int bi) {
    const int k0 = t * BK;
    short* at = As[bi];
    short* bt = Bs[bi];
#pragma unroll
    for (int li = 0; li < 2; ++li) {
      int rb = (w * 2 + li) * 8;
      glds16(aSrc + (size_t)(rb + srow) * lda + k0 + scol, at + rb * BK);
    }
#pragma unroll
    for (int li = 0; li < 2; ++li) {
      int rb = (w * 2 + li) * 8;
      glds16(bSrc + (size_t)(rb + srow) * ldb + k0 + scol, bt + rb * BK);
    }
  };

  f32x4 acc[2][2];
#pragma unroll
  for (int a = 0; a < 2; a++)
#pragma unroll
    for (int b = 0; b < 2; b++) acc[a][b] = (f32x4){0.f, 0.f, 0.f, 0.f};

  STAGE(0, 0);
  STAGE(1, 1);
  STAGE(2, 2);

  int bufi = 0;
  for (int t = 0; t < NT; ++t) {
    // drain so stage(t) is complete; keep up to 2 later stages in flight
    if (t < NT - 2)      wait_vm<8>();
    else if (t == NT - 2) wait_vm<4>();
    else                  wait_vm<0>();
    __builtin_amdgcn_s_barrier();
    asm volatile("" ::: "memory");

    const short* at = As[bufi];
    const short* bt = Bs[bufi];
#pragma unroll
    for (int kk = 0; kk < 2; ++kk) {
      const int cb = kk * 4 + (lane >> 4);
      short8 af[2], bfr[2];
#pragma unroll
      for (int a = 0; a < 2; ++a) {
        int ra = wrow * 32 + a * 16 + l15;
        int c = cb ^ (ra & 7);
        af[a] = *(const short8*)(at + ra * BK + c * 8);
      }
#pragma unroll
      for (int b = 0; b < 2; ++b) {
        int rb = wcol * 32 + b * 16 + l15;
        int c = cb ^ (rb & 7);
        bfr[b] = *(const short8*)(bt + rb * BK + c * 8);
      }
      __builtin_amdgcn_s_setprio(1);
#pragma unroll
      for (int a = 0; a < 2; ++a)
#pragma unroll
        for (int b = 0; b < 2; ++b)
          acc[a][b] = __builtin_amdgcn_mfma_f32_16x16x32_bf16(af[a], bfr[b], acc[a][b], 0, 0, 0);
      __builtin_amdgcn_s_setprio(0);
    }

    asm volatile("" ::: "memory");
    __builtin_amdgcn_s_barrier();
    asm volatile("" ::: "memory");
    if (t + 3 < NT) STAGE(t + 3, bufi);   // (t+3) % 3 == t % 3 == bufi
    bufi = (bufi == 2) ? 0 : bufi + 1;
  }

  const float hv = hptr[0];
  const int ibase = i0 + wrow * 32 + ((lane >> 4) << 2);
#pragma unroll
  for (int a = 0; a < 2; ++a) {
    const int ia = ibase + a * 16;
#pragma unroll
    for (int b = 0; b < 2; ++b) {
      const int jb = j0 + wcol * 32 + b * 16 + l15;
      f32x4 c = acc[a][b];
      if (MODE == 0) {
#pragma unroll
        for (int q = 0; q < 4; ++q) {
          size_t off = (size_t)(ia + q) * NN + jb;
          Fout[off] = c[q];
          if (ia + q < 1024) Bout[off] = f2bf(c[q]);
        }
      } else if (MODE == 1) {
#pragma unroll
        for (int p = 0; p < 4; p += 2) {
          size_t offr = (size_t)(ia + p) * NN + jb;
          size_t offi = offr + NN;
          float vr = Vin[offr], vi = Vin[offi];
          float outr = hv * (vr - c[p])     + vi;
          float outi = hv * (vi - c[p + 1]) - vr;
          Fout[offr] = outr; Fout[offi] = outi;
          Bout[offr] = f2bf(outr); Bout[offi] = f2bf(outi);
        }
      } else {
#pragma unroll
        for (int p = 0; p < 4; p += 2) {
          size_t offr = (size_t)(ia + p) * NN + jb;
          size_t offi = offr + NN;
          float2 dv = dinv[jb];
          float vr = Vin[offr], vi = Vin[offi];
          float yr = Yin[offr], yi = Yin[offi];
          float tr_ = hv * (yr - c[p])     - yi;
          float ti_ = hv * (yi - c[p + 1]) + yr;
          float er = vr - tr_, ei = vi - ti_;
          float nyr = yr + dv.x * er - dv.y * ei;
          float nyi = yi + dv.x * ei + dv.y * er;
          Fout[offr] = nyr; Fout[offi] = nyi;
          Bout[offr] = f2bf(nyr); Bout[offi] = f2bf(nyi);
        }
      }
    }
  }
}

// ---------------- final: out[node][c] = relu(out0T[c][node] + 2*(term1 + term2)) ----------------
__global__ __launch_bounds__(256) void final_out(
    const float* __restrict__ Vbuf,
    const float* __restrict__ ybuf,
    float* __restrict__ out)
{
  __shared__ float t[64][65];
  int n0 = blockIdx.x * 64;
  int c0 = blockIdx.y * 64;
  int lane = threadIdx.x & 63;
  int wv = threadIdx.x >> 6;
#pragma unroll
  for (int s = 0; s < 16; s++) {
    int c = c0 + wv + s * 4;
    float o0 = Vbuf[(size_t)(1024 + c) * NN + n0 + lane];
    float u  = ybuf[(size_t)(2 * c) * NN + n0 + lane];
    float sv = ybuf[(size_t)(512 + 2 * c) * NN + n0 + lane];
    float v = o0 + 2.f * (u + sv);
    t[lane][wv + s * 4] = v > 0.f ? v : 0.f;
  }
  __syncthreads();
#pragma unroll
  for (int s = 0; s < 16; s++) {
    int nl = wv + s * 4;
    out[(size_t)(n0 + nl) * FOUT + c0 + lane] = t[nl][lane];
  }
}

extern "C" void kernel_launch(void* const* d_in, const int* in_sizes, int n_in,
                              void* d_out, int out_size, void* d_ws, size_t ws_size,
                              hipStream_t stream) {
  const float* x   = (const float*)d_in[0];
  const float* adj = (const float*)d_in[1];
  const float* h   = (const float*)d_in[2];
  const float* w0  = (const float*)d_in[3];
  const float* wr  = (const float*)d_in[4];
  const float* wi  = (const float*)d_in[5];
  float* out = (float*)d_out;

  char* ws = (char*)d_ws;
  size_t off = 0;
  auto alloc = [&](size_t bytes) {
    char* p = ws + off;
    off += (bytes + 255) & ~(size_t)255;
    return p;
  };
  short*  adjbf = (short*)alloc((size_t)NN * NN * 2);
  short*  xbf   = (short*)alloc((size_t)NN * FIN * 2);
  short*  wpack = (short*)alloc((size_t)1280 * FIN * 2);
  float2* dinv  = (float2*)alloc((size_t)NN * sizeof(float2));
  float*  Vbuf  = (float*)alloc((size_t)1280 * NN * 4);
  float*  ybuf  = (float*)alloc((size_t)1024 * NN * 4);
  short*  b0    = (short*)alloc((size_t)1024 * NN * 2);
  short*  b1    = (short*)alloc((size_t)1024 * NN * 2);

  prep_adj<<<NN, 256, 0, stream>>>(adj, adjbf, dinv, h);
  prep_xw<<<4096, 256, 0, stream>>>(x, w0, wr, wi, xbf, wpack);

  // GEMM0: [1280][3072] = wpack @ xbf^T, K=512 -> Vbuf (P1|P0|out0T), b0 bf16
  gemm_t<0, FIN, 20><<<dim3(48 * 20), 256, 0, stream>>>(
      wpack, FIN, xbf, FIN, nullptr, nullptr, Vbuf, b0, dinv, h);
  // wide A (rows 0-1023): V' = A([P1;P0]), in-place Vbuf
  gemm_t<1, NN, 16><<<dim3(48 * 16), 256, 0, stream>>>(
      b0, NN, adjbf, NN, Vbuf, nullptr, Vbuf, b1, dinv, h);
  // wide G x3
  gemm_t<2, NN, 16><<<dim3(48 * 16), 256, 0, stream>>>(
      b1, NN, adjbf, NN, Vbuf, Vbuf, ybuf, b0, dinv, h);
  gemm_t<2, NN, 16><<<dim3(48 * 16), 256, 0, stream>>>(
      b0, NN, adjbf, NN, Vbuf, ybuf, ybuf, b1, dinv, h);
  gemm_t<2, NN, 16><<<dim3(48 * 16), 256, 0, stream>>>(
      b1, NN, adjbf, NN, Vbuf, ybuf, ybuf, b0, dinv, h);
  // narrow A (chain-2 rows 0-511): input = ybuf rows 0-511, out -> Vbuf rows 0-511
  gemm_t<1, NN, 8><<<dim3(48 * 8), 256, 0, stream>>>(
      b0, NN, adjbf, NN, ybuf, nullptr, Vbuf, b1, dinv, h);
  // narrow G x3
  gemm_t<2, NN, 8><<<dim3(48 * 8), 256, 0, stream>>>(
      b1, NN, adjbf, NN, Vbuf, Vbuf, ybuf, b0, dinv, h);
  gemm_t<2, NN, 8><<<dim3(48 * 8), 256, 0, stream>>>(
      b0, NN, adjbf, NN, Vbuf, ybuf, ybuf, b1, dinv, h);
  gemm_t<2, NN, 8><<<dim3(48 * 8), 256, 0, stream>>>(
      b1, NN, adjbf, NN, Vbuf, ybuf, ybuf, b0, dinv, h);

  final_out<<<dim3(48, 4), 256, 0, stream>>>(Vbuf, ybuf, out);
}

// Round 11
// 370.288 us; speedup vs baseline: 1.0429x; 1.0429x over previous
//
#include <hip/hip_runtime.h>
#include <hip/hip_bf16.h>

#define NN 3072
#define FIN 512
#define FOUT 256

typedef __attribute__((ext_vector_type(8))) short short8;
typedef __attribute__((ext_vector_type(4))) float f32x4;

__device__ __forceinline__ short f2bf(float f) {
  union { float f; unsigned u; } v; v.f = f;
  unsigned r = v.u + 0x7fffu + ((v.u >> 16) & 1u);  // RNE
  return (short)(r >> 16);
}

__device__ __forceinline__ void glds16(const short* g, short* l) {
  __builtin_amdgcn_global_load_lds(
      (const __attribute__((address_space(1))) unsigned*)g,
      (__attribute__((address_space(3))) unsigned*)l, 16, 0, 0);
}

template<int N> __device__ __forceinline__ void wait_vm() {
  if constexpr (N == 0) asm volatile("s_waitcnt vmcnt(0)" ::: "memory");
  else                  asm volatile("s_waitcnt vmcnt(4)" ::: "memory");
}

// ---------------- prep kernels (verified) ----------------

__global__ __launch_bounds__(256) void prep_adj(const float* __restrict__ adj,
    short* __restrict__ adjbf, float2* __restrict__ dinv, const float* __restrict__ hptr)
{
  int m = blockIdx.x;
  int tid = threadIdx.x;
  const float4* row = (const float4*)(adj + (size_t)m * NN);
  short4* obf = (short4*)(adjbf + (size_t)m * NN);
  float sum = 0.f;
#pragma unroll
  for (int i = 0; i < NN / 4 / 256; ++i) {
    int idx = i * 256 + tid;
    float4 v = row[idx];
    sum += (v.x + v.y) + (v.z + v.w);
    obf[idx] = make_short4(f2bf(v.x), f2bf(v.y), f2bf(v.z), f2bf(v.w));
  }
#pragma unroll
  for (int off = 32; off > 0; off >>= 1) sum += __shfl_down(sum, off, 64);
  __shared__ float red[4];
  if ((tid & 63) == 0) red[tid >> 6] = sum;
  __syncthreads();
  if (tid == 0) {
    float s = red[0] + red[1] + red[2] + red[3];
    float h = hptr[0];
    float r = h * (1.f - s);
    float den = r * r + 1.f;
    dinv[m] = make_float2(r / den, -1.f / den);
  }
}

// merged prep_x (blocks 0..1535) + prep_w (blocks 1536..4095)  [r8-verified]
__global__ __launch_bounds__(256) void prep_xw(const float* __restrict__ x,
    const float* __restrict__ w0, const float* __restrict__ wr,
    const float* __restrict__ wi, short* __restrict__ xbf, short* __restrict__ wpack)
{
  int b = blockIdx.x;
  if (b < 1536) {
    int idx = b * 256 + threadIdx.x;
    float4 v = ((const float4*)x)[idx];
    ((short4*)xbf)[idx] = make_short4(f2bf(v.x), f2bf(v.y), f2bf(v.z), f2bf(v.w));
  } else {
    int idx = (b - 1536) * 256 + threadIdx.x;   // [1280][512]
    int f = idx & 511;
    int i = idx >> 9;
    float v;
    if (i < 1024) {
      int j = (i < 512) ? 1 : 0;
      int local = i & 511;
      int c = local >> 1;
      const float* src = (local & 1) ? wi : wr;
      v = src[((size_t)j * FIN + f) * FOUT + c];
    } else {
      v = w0[(size_t)f * FOUT + (i - 1024)];
    }
    wpack[idx] = f2bf(v);
  }
}

// ---------------- 64x64-tile GEMM, double-buffered, counted vmcnt (R7-verified) ----------------
// 4 waves (2x2 of 32x32). BK=64. LDS 32KB. XCD-clustered decode.
// MODE 0: plain write (+bf16 for rows<1024)
// MODE 1: A-op epilogue   out = hL@V - iV
// MODE 2: Jacobi epilogue y' = y + dinv*(V - (hL@y + iy))
// MODE 3: MODE 2 then += Min (fused chain merge: W = y' + Q0)
template<int MODE, int KTOT, int ITILES>
__global__ __launch_bounds__(256, 4) void gemm_t(
    const short* __restrict__ Apan, int lda,
    const short* __restrict__ Badj, int ldb,
    const float* __restrict__ Vin,
    const float* __restrict__ Yin,
    const float* __restrict__ Min,
    float* __restrict__ Fout,
    short* __restrict__ Bout,
    const float2* __restrict__ dinv,
    const float* __restrict__ hptr)
{
  constexpr int BK = 64;
  constexpr int NT = KTOT / BK;

  __shared__ short As[2][64 * BK];
  __shared__ short Bs[2][64 * BK];

  const int tid  = threadIdx.x;
  const int lane = tid & 63;
  const int w    = tid >> 6;
  const int l15  = lane & 15;
  const int wrow = w >> 1, wcol = w & 1;

  // XCD-clustered decode: 8 XCDs x 6 j-columns x ITILES
  const int bid = blockIdx.x;
  const int xcd = bid & 7;
  const int s   = bid >> 3;
  const int jt  = xcd * 6 + s / ITILES;
  const int it  = s % ITILES;

  const int i0 = it * 64;
  const int j0 = jt * 64;

  const int srow = lane >> 3;                 // 0..7
  const int scol = ((lane & 7) ^ srow) * 8;   // source chunk XOR-swizzle (r2/r5/r7)

  const short* aSrc = Apan + (size_t)i0 * lda;
  const short* bSrc = Badj + (size_t)j0 * ldb;

  auto STAGE = [&](int t) {
    const int k0 = t * BK;
    short* at = As[t & 1];
    short* bt = Bs[t & 1];
#pragma unroll
    for (int li = 0; li < 2; ++li) {
      int rb = (w * 2 + li) * 8;
      glds16(aSrc + (size_t)(rb + srow) * lda + k0 + scol, at + rb * BK);
    }
#pragma unroll
    for (int li = 0; li < 2; ++li) {
      int rb = (w * 2 + li) * 8;
      glds16(bSrc + (size_t)(rb + srow) * ldb + k0 + scol, bt + rb * BK);
    }
  };

  f32x4 acc[2][2];
#pragma unroll
  for (int a = 0; a < 2; a++)
#pragma unroll
    for (int b = 0; b < 2; b++) acc[a][b] = (f32x4){0.f, 0.f, 0.f, 0.f};

  STAGE(0);
  STAGE(1);

  for (int t = 0; t < NT; ++t) {
    if (t < NT - 1) wait_vm<4>(); else wait_vm<0>();
    __builtin_amdgcn_s_barrier();
    asm volatile("" ::: "memory");

    const short* at = As[t & 1];
    const short* bt = Bs[t & 1];
#pragma unroll
    for (int kk = 0; kk < 2; ++kk) {
      const int cb = kk * 4 + (lane >> 4);
      short8 af[2], bfr[2];
#pragma unroll
      for (int a = 0; a < 2; ++a) {
        int ra = wrow * 32 + a * 16 + l15;
        int c = cb ^ (ra & 7);
        af[a] = *(const short8*)(at + ra * BK + c * 8);
      }
#pragma unroll
      for (int b = 0; b < 2; ++b) {
        int rb = wcol * 32 + b * 16 + l15;
        int c = cb ^ (rb & 7);
        bfr[b] = *(const short8*)(bt + rb * BK + c * 8);
      }
      __builtin_amdgcn_s_setprio(1);
#pragma unroll
      for (int a = 0; a < 2; ++a)
#pragma unroll
        for (int b = 0; b < 2; ++b)
          acc[a][b] = __builtin_amdgcn_mfma_f32_16x16x32_bf16(af[a], bfr[b], acc[a][b], 0, 0, 0);
      __builtin_amdgcn_s_setprio(0);
    }

    asm volatile("" ::: "memory");
    __builtin_amdgcn_s_barrier();
    asm volatile("" ::: "memory");
    if (t + 2 < NT) STAGE(t + 2);
  }

  const float hv = hptr[0];
  const int ibase = i0 + wrow * 32 + ((lane >> 4) << 2);
#pragma unroll
  for (int a = 0; a < 2; ++a) {
    const int ia = ibase + a * 16;
#pragma unroll
    for (int b = 0; b < 2; ++b) {
      const int jb = j0 + wcol * 32 + b * 16 + l15;
      f32x4 c = acc[a][b];
      if (MODE == 0) {
#pragma unroll
        for (int q = 0; q < 4; ++q) {
          size_t off = (size_t)(ia + q) * NN + jb;
          Fout[off] = c[q];
          if (ia + q < 1024) Bout[off] = f2bf(c[q]);
        }
      } else if (MODE == 1) {
#pragma unroll
        for (int p = 0; p < 4; p += 2) {
          size_t offr = (size_t)(ia + p) * NN + jb;
          size_t offi = offr + NN;
          float vr = Vin[offr], vi = Vin[offi];
          float outr = hv * (vr - c[p])     + vi;
          float outi = hv * (vi - c[p + 1]) - vr;
          Fout[offr] = outr; Fout[offi] = outi;
          Bout[offr] = f2bf(outr); Bout[offi] = f2bf(outi);
        }
      } else {
#pragma unroll
        for (int p = 0; p < 4; p += 2) {
          size_t offr = (size_t)(ia + p) * NN + jb;
          size_t offi = offr + NN;
          float2 dv = dinv[jb];
          float vr = Vin[offr], vi = Vin[offi];
          float yr = Yin[offr], yi = Yin[offi];
          float tr_ = hv * (yr - c[p])     - yi;
          float ti_ = hv * (yi - c[p + 1]) + yr;
          float er = vr - tr_, ei = vi - ti_;
          float nyr = yr + dv.x * er - dv.y * ei;
          float nyi = yi + dv.x * ei + dv.y * er;
          if (MODE == 3) {            // fused merge: W = y' + Q0
            nyr += Min[offr];
            nyi += Min[offi];
          }
          Fout[offr] = nyr; Fout[offi] = nyi;
          Bout[offr] = f2bf(nyr); Bout[offi] = f2bf(nyi);
        }
      }
    }
  }
}

// ---------------- final: out[node][c] = relu(out0T[c][node] + 2*csum_r[c][node]) ----------------
__global__ __launch_bounds__(256) void final_out(
    const float* __restrict__ Vbuf,   // rows 1024..1279 = out0T
    const float* __restrict__ ybuf,   // final chain output, rows 2c = Re
    float* __restrict__ out)
{
  __shared__ float t[64][65];
  int n0 = blockIdx.x * 64;
  int c0 = blockIdx.y * 64;
  int lane = threadIdx.x & 63;
  int wv = threadIdx.x >> 6;
#pragma unroll
  for (int s = 0; s < 16; s++) {
    int c = c0 + wv + s * 4;
    float o0 = Vbuf[(size_t)(1024 + c) * NN + n0 + lane];
    float u  = ybuf[(size_t)(2 * c) * NN + n0 + lane];
    float v = o0 + 2.f * u;
    t[lane][wv + s * 4] = v > 0.f ? v : 0.f;
  }
  __syncthreads();
#pragma unroll
  for (int s = 0; s < 16; s++) {
    int nl = wv + s * 4;
    out[(size_t)(n0 + nl) * FOUT + c0 + lane] = t[nl][lane];
  }
}

extern "C" void kernel_launch(void* const* d_in, const int* in_sizes, int n_in,
                              void* d_out, int out_size, void* d_ws, size_t ws_size,
                              hipStream_t stream) {
  const float* x   = (const float*)d_in[0];
  const float* adj = (const float*)d_in[1];
  const float* h   = (const float*)d_in[2];
  const float* w0  = (const float*)d_in[3];
  const float* wr  = (const float*)d_in[4];
  const float* wi  = (const float*)d_in[5];
  float* out = (float*)d_out;

  char* ws = (char*)d_ws;
  size_t off = 0;
  auto alloc = [&](size_t bytes) {
    char* p = ws + off;
    off += (bytes + 255) & ~(size_t)255;
    return p;
  };
  short*  adjbf = (short*)alloc((size_t)NN * NN * 2);
  short*  xbf   = (short*)alloc((size_t)NN * FIN * 2);
  short*  wpack = (short*)alloc((size_t)1280 * FIN * 2);
  float2* dinv  = (float2*)alloc((size_t)NN * sizeof(float2));
  float*  Vbuf  = (float*)alloc((size_t)1280 * NN * 4);  // Q1 | Q0 | out0T
  float*  xjbuf = (float*)alloc((size_t)512 * NN * 4);   // rhs / merged W
  float*  ybuf  = (float*)alloc((size_t)512 * NN * 4);   // Jacobi y
  short*  b0    = (short*)alloc((size_t)1024 * NN * 2);  // GEMM0 bf16 out
  short*  b1    = (short*)alloc((size_t)512 * NN * 2);
  short*  b2    = (short*)alloc((size_t)512 * NN * 2);

  prep_adj<<<NN, 256, 0, stream>>>(adj, adjbf, dinv, h);
  prep_xw<<<4096, 256, 0, stream>>>(x, w0, wr, wi, xbf, wpack);

  const float* Q0f = Vbuf + (size_t)512 * NN;

  // GEMM0: [1280][3072] = wpack @ xbf^T, K=512 -> Vbuf (Q1|Q0|out0T), b0 bf16
  gemm_t<0, FIN, 20><<<dim3(48 * 20), 256, 0, stream>>>(
      wpack, FIN, xbf, FIN, nullptr, nullptr, nullptr, Vbuf, b0, dinv, h);

  // ---- chain 1: Z = (G∘A)(Q1), fused merge W = Z + Q0 in last Jacobi ----
  // A: xj = hL@Q1 - i Q1
  gemm_t<1, NN, 8><<<dim3(48 * 8), 256, 0, stream>>>(
      b0, NN, adjbf, NN, Vbuf, nullptr, nullptr, xjbuf, b1, dinv, h);
  // G1: y1 = xj + dinv*(xj - (hL@xj + i xj))
  gemm_t<2, NN, 8><<<dim3(48 * 8), 256, 0, stream>>>(
      b1, NN, adjbf, NN, xjbuf, xjbuf, nullptr, ybuf, b2, dinv, h);
  // G2
  gemm_t<2, NN, 8><<<dim3(48 * 8), 256, 0, stream>>>(
      b2, NN, adjbf, NN, xjbuf, ybuf, nullptr, ybuf, b1, dinv, h);
  // G3 + merge: W = y3 + Q0  (f32 -> xjbuf, bf16 -> b2)
  gemm_t<3, NN, 8><<<dim3(48 * 8), 256, 0, stream>>>(
      b1, NN, adjbf, NN, xjbuf, ybuf, Q0f, xjbuf, b2, dinv, h);

  // ---- chain 2: csum = (G∘A)(W) ----
  // A: xj = hL@W - i W   (in-place xjbuf: element-aligned, safe)
  gemm_t<1, NN, 8><<<dim3(48 * 8), 256, 0, stream>>>(
      b2, NN, adjbf, NN, xjbuf, nullptr, nullptr, xjbuf, b1, dinv, h);
  // G1
  gemm_t<2, NN, 8><<<dim3(48 * 8), 256, 0, stream>>>(
      b1, NN, adjbf, NN, xjbuf, xjbuf, nullptr, ybuf, b2, dinv, h);
  // G2
  gemm_t<2, NN, 8><<<dim3(48 * 8), 256, 0, stream>>>(
      b2, NN, adjbf, NN, xjbuf, ybuf, nullptr, ybuf, b1, dinv, h);
  // G3 -> final csum panel (bf16 out unused)
  gemm_t<2, NN, 8><<<dim3(48 * 8), 256, 0, stream>>>(
      b1, NN, adjbf, NN, xjbuf, ybuf, nullptr, ybuf, b2, dinv, h);

  final_out<<<dim3(48, 4), 256, 0, stream>>>(Vbuf, ybuf, out);
}

// Round 12
// 338.029 us; speedup vs baseline: 1.1424x; 1.0954x over previous
//
#include <hip/hip_runtime.h>
#include <hip/hip_bf16.h>

#define NN 3072
#define FIN 512
#define FOUT 256

typedef __attribute__((ext_vector_type(8))) short short8;
typedef __attribute__((ext_vector_type(4))) float f32x4;

__device__ __forceinline__ short f2bf(float f) {
  union { float f; unsigned u; } v; v.f = f;
  unsigned r = v.u + 0x7fffu + ((v.u >> 16) & 1u);  // RNE
  return (short)(r >> 16);
}

__device__ __forceinline__ void glds16(const short* g, short* l) {
  __builtin_amdgcn_global_load_lds(
      (const __attribute__((address_space(1))) unsigned*)g,
      (__attribute__((address_space(3))) unsigned*)l, 16, 0, 0);
}

template<int N> __device__ __forceinline__ void wait_vm() {
  if constexpr (N == 0)      asm volatile("s_waitcnt vmcnt(0)" ::: "memory");
  else if constexpr (N == 3) asm volatile("s_waitcnt vmcnt(3)" ::: "memory");
  else                       asm volatile("s_waitcnt vmcnt(4)" ::: "memory");
}

// ---------------- prep kernels (verified) ----------------

__global__ __launch_bounds__(256) void prep_adj(const float* __restrict__ adj,
    short* __restrict__ adjbf, float2* __restrict__ dinv, const float* __restrict__ hptr)
{
  int m = blockIdx.x;
  int tid = threadIdx.x;
  const float4* row = (const float4*)(adj + (size_t)m * NN);
  short4* obf = (short4*)(adjbf + (size_t)m * NN);
  float sum = 0.f;
#pragma unroll
  for (int i = 0; i < NN / 4 / 256; ++i) {
    int idx = i * 256 + tid;
    float4 v = row[idx];
    sum += (v.x + v.y) + (v.z + v.w);
    obf[idx] = make_short4(f2bf(v.x), f2bf(v.y), f2bf(v.z), f2bf(v.w));
  }
#pragma unroll
  for (int off = 32; off > 0; off >>= 1) sum += __shfl_down(sum, off, 64);
  __shared__ float red[4];
  if ((tid & 63) == 0) red[tid >> 6] = sum;
  __syncthreads();
  if (tid == 0) {
    float s = red[0] + red[1] + red[2] + red[3];
    float h = hptr[0];
    float r = h * (1.f - s);
    float den = r * r + 1.f;
    dinv[m] = make_float2(r / den, -1.f / den);
  }
}

// merged prep_x (blocks 0..1535) + prep_w (blocks 1536..4095)  [r8-verified]
__global__ __launch_bounds__(256) void prep_xw(const float* __restrict__ x,
    const float* __restrict__ w0, const float* __restrict__ wr,
    const float* __restrict__ wi, short* __restrict__ xbf, short* __restrict__ wpack)
{
  int b = blockIdx.x;
  if (b < 1536) {
    int idx = b * 256 + threadIdx.x;
    float4 v = ((const float4*)x)[idx];
    ((short4*)xbf)[idx] = make_short4(f2bf(v.x), f2bf(v.y), f2bf(v.z), f2bf(v.w));
  } else {
    int idx = (b - 1536) * 256 + threadIdx.x;   // [1280][512]
    int f = idx & 511;
    int i = idx >> 9;
    float v;
    if (i < 1024) {
      int j = (i < 512) ? 1 : 0;
      int local = i & 511;
      int c = local >> 1;
      const float* src = (local & 1) ? wi : wr;
      v = src[((size_t)j * FIN + f) * FOUT + c];
    } else {
      v = w0[(size_t)f * FOUT + (i - 1024)];
    }
    wpack[idx] = f2bf(v);
  }
}

// ---------------- BMx64-tile GEMM, double-buffered, counted vmcnt ----------------
// BM=64: 4 waves 2x2, 32x32/wave (R7-verified geometry).
// BM=32: 4 waves 1x4, 32x16/wave -> M=512 ops get 16x48=768 blocks = 3/CU.
// BK=64. XOR source/read swizzle, XCD-clustered decode (6 j-cols per XCD).
// MODE 0: plain write (+bf16 for rows<1024)
// MODE 1: A-op epilogue   out = hL@V - iV
// MODE 2: Jacobi epilogue y' = y + dinv*(V - (hL@y + iy))
// MODE 3: MODE 2 then += Min (fused chain merge)
template<int BM, int MODE, int KTOT, int ITILES>
__global__ __launch_bounds__(256, 4) void gemm_t(
    const short* __restrict__ Apan, int lda,
    const short* __restrict__ Badj, int ldb,
    const float* __restrict__ Vin,
    const float* __restrict__ Yin,
    const float* __restrict__ Min,
    float* __restrict__ Fout,
    short* __restrict__ Bout,
    const float2* __restrict__ dinv,
    const float* __restrict__ hptr)
{
  constexpr int BK = 64;
  constexpr int BN = 64;
  constexpr int NT = KTOT / BK;
  constexpr int WC  = (BM == 64) ? 2 : 4;   // waves along N
  constexpr int NR  = (BM == 64) ? 2 : 1;   // 16-col frags per wave
  constexpr int WN  = BN / WC;              // wave col extent (32 / 16)
  constexpr int LPW = BM / 32 + 2;          // glds16 per wave per stage

  __shared__ short As[2][BM * BK];
  __shared__ short Bs[2][BN * BK];

  const int tid  = threadIdx.x;
  const int lane = tid & 63;
  const int w    = tid >> 6;
  const int l15  = lane & 15;
  const int wrow = w / WC, wcol = w % WC;

  // XCD-clustered decode: 8 XCDs x 6 j-columns x ITILES
  const int bid = blockIdx.x;
  const int xcd = bid & 7;
  const int s   = bid >> 3;
  const int jt  = xcd * 6 + s / ITILES;
  const int it  = s % ITILES;

  const int i0 = it * BM;
  const int j0 = jt * BN;

  const int srow = lane >> 3;                 // 0..7
  const int scol = ((lane & 7) ^ srow) * 8;   // source chunk XOR-swizzle (r2/r5/r7)

  const short* aSrc = Apan + (size_t)i0 * lda;
  const short* bSrc = Badj + (size_t)j0 * ldb;

  auto STAGE = [&](int t) {
    const int k0 = t * BK;
    short* at = As[t & 1];
    short* bt = Bs[t & 1];
#pragma unroll
    for (int li = 0; li < BM / 32; ++li) {
      int rb = (w + li * 4) * 8;
      glds16(aSrc + (size_t)(rb + srow) * lda + k0 + scol, at + rb * BK);
    }
#pragma unroll
    for (int li = 0; li < 2; ++li) {
      int rb = (w + li * 4) * 8;
      glds16(bSrc + (size_t)(rb + srow) * ldb + k0 + scol, bt + rb * BK);
    }
  };

  f32x4 acc[2][NR];
#pragma unroll
  for (int a = 0; a < 2; a++)
#pragma unroll
    for (int b = 0; b < NR; b++) acc[a][b] = (f32x4){0.f, 0.f, 0.f, 0.f};

  STAGE(0);
  STAGE(1);

  for (int t = 0; t < NT; ++t) {
    if (t < NT - 1) wait_vm<LPW>(); else wait_vm<0>();
    __builtin_amdgcn_s_barrier();
    asm volatile("" ::: "memory");

    const short* at = As[t & 1];
    const short* bt = Bs[t & 1];
#pragma unroll
    for (int kk = 0; kk < 2; ++kk) {
      const int cb = kk * 4 + (lane >> 4);
      short8 af[2], bfr[NR];
#pragma unroll
      for (int a = 0; a < 2; ++a) {
        int ra = wrow * 32 + a * 16 + l15;
        int c = cb ^ (ra & 7);
        af[a] = *(const short8*)(at + ra * BK + c * 8);
      }
#pragma unroll
      for (int b = 0; b < NR; ++b) {
        int rb = wcol * WN + b * 16 + l15;
        int c = cb ^ (rb & 7);
        bfr[b] = *(const short8*)(bt + rb * BK + c * 8);
      }
      __builtin_amdgcn_s_setprio(1);
#pragma unroll
      for (int a = 0; a < 2; ++a)
#pragma unroll
        for (int b = 0; b < NR; ++b)
          acc[a][b] = __builtin_amdgcn_mfma_f32_16x16x32_bf16(af[a], bfr[b], acc[a][b], 0, 0, 0);
      __builtin_amdgcn_s_setprio(0);
    }

    asm volatile("" ::: "memory");
    __builtin_amdgcn_s_barrier();
    asm volatile("" ::: "memory");
    if (t + 2 < NT) STAGE(t + 2);
  }

  const float hv = hptr[0];
  const int ibase = i0 + wrow * 32 + ((lane >> 4) << 2);
#pragma unroll
  for (int a = 0; a < 2; ++a) {
    const int ia = ibase + a * 16;
#pragma unroll
    for (int b = 0; b < NR; ++b) {
      const int jb = j0 + wcol * WN + b * 16 + l15;
      f32x4 c = acc[a][b];
      if (MODE == 0) {
#pragma unroll
        for (int q = 0; q < 4; ++q) {
          size_t off = (size_t)(ia + q) * NN + jb;
          Fout[off] = c[q];
          if (ia + q < 1024) Bout[off] = f2bf(c[q]);
        }
      } else if (MODE == 1) {
#pragma unroll
        for (int p = 0; p < 4; p += 2) {
          size_t offr = (size_t)(ia + p) * NN + jb;
          size_t offi = offr + NN;
          float vr = Vin[offr], vi = Vin[offi];
          float outr = hv * (vr - c[p])     + vi;
          float outi = hv * (vi - c[p + 1]) - vr;
          Fout[offr] = outr; Fout[offi] = outi;
          Bout[offr] = f2bf(outr); Bout[offi] = f2bf(outi);
        }
      } else {
#pragma unroll
        for (int p = 0; p < 4; p += 2) {
          size_t offr = (size_t)(ia + p) * NN + jb;
          size_t offi = offr + NN;
          float2 dv = dinv[jb];
          float vr = Vin[offr], vi = Vin[offi];
          float yr = Yin[offr], yi = Yin[offi];
          float tr_ = hv * (yr - c[p])     - yi;
          float ti_ = hv * (yi - c[p + 1]) + yr;
          float er = vr - tr_, ei = vi - ti_;
          float nyr = yr + dv.x * er - dv.y * ei;
          float nyi = yi + dv.x * ei + dv.y * er;
          if (MODE == 3) {            // fused merge: W = y' + Q0
            nyr += Min[offr];
            nyi += Min[offi];
          }
          Fout[offr] = nyr; Fout[offi] = nyi;
          Bout[offr] = f2bf(nyr); Bout[offi] = f2bf(nyi);
        }
      }
    }
  }
}

// ---------------- final: out[node][c] = relu(out0T[c][node] + 2*csum_r[c][node]) ----------------
__global__ __launch_bounds__(256) void final_out(
    const float* __restrict__ Vbuf,   // rows 1024..1279 = out0T
    const float* __restrict__ ybuf,   // final chain output, rows 2c = Re
    float* __restrict__ out)
{
  __shared__ float t[64][65];
  int n0 = blockIdx.x * 64;
  int c0 = blockIdx.y * 64;
  int lane = threadIdx.x & 63;
  int wv = threadIdx.x >> 6;
#pragma unroll
  for (int s = 0; s < 16; s++) {
    int c = c0 + wv + s * 4;
    float o0 = Vbuf[(size_t)(1024 + c) * NN + n0 + lane];
    float u  = ybuf[(size_t)(2 * c) * NN + n0 + lane];
    float v = o0 + 2.f * u;
    t[lane][wv + s * 4] = v > 0.f ? v : 0.f;
  }
  __syncthreads();
#pragma unroll
  for (int s = 0; s < 16; s++) {
    int nl = wv + s * 4;
    out[(size_t)(n0 + nl) * FOUT + c0 + lane] = t[nl][lane];
  }
}

extern "C" void kernel_launch(void* const* d_in, const int* in_sizes, int n_in,
                              void* d_out, int out_size, void* d_ws, size_t ws_size,
                              hipStream_t stream) {
  const float* x   = (const float*)d_in[0];
  const float* adj = (const float*)d_in[1];
  const float* h   = (const float*)d_in[2];
  const float* w0  = (const float*)d_in[3];
  const float* wr  = (const float*)d_in[4];
  const float* wi  = (const float*)d_in[5];
  float* out = (float*)d_out;

  char* ws = (char*)d_ws;
  size_t off = 0;
  auto alloc = [&](size_t bytes) {
    char* p = ws + off;
    off += (bytes + 255) & ~(size_t)255;
    return p;
  };
  short*  adjbf = (short*)alloc((size_t)NN * NN * 2);
  short*  xbf   = (short*)alloc((size_t)NN * FIN * 2);
  short*  wpack = (short*)alloc((size_t)1280 * FIN * 2);
  float2* dinv  = (float2*)alloc((size_t)NN * sizeof(float2));
  float*  Vbuf  = (float*)alloc((size_t)1280 * NN * 4);  // Q1 | Q0 | out0T
  float*  xjbuf = (float*)alloc((size_t)512 * NN * 4);   // rhs / merged W
  float*  ybuf  = (float*)alloc((size_t)512 * NN * 4);   // Jacobi y
  short*  b0    = (short*)alloc((size_t)1024 * NN * 2);  // GEMM0 bf16 out
  short*  b1    = (short*)alloc((size_t)512 * NN * 2);
  short*  b2    = (short*)alloc((size_t)512 * NN * 2);

  prep_adj<<<NN, 256, 0, stream>>>(adj, adjbf, dinv, h);
  prep_xw<<<4096, 256, 0, stream>>>(x, w0, wr, wi, xbf, wpack);

  const float* Q0f = Vbuf + (size_t)512 * NN;

  // GEMM0: [1280][3072] = wpack @ xbf^T, K=512 -> Vbuf (Q1|Q0|out0T), b0 bf16
  gemm_t<64, 0, FIN, 20><<<dim3(48 * 20), 256, 0, stream>>>(
      wpack, FIN, xbf, FIN, nullptr, nullptr, nullptr, Vbuf, b0, dinv, h);

  // ---- chain 1: Z = (G∘A)(Q1), fused merge W = Z + Q0 in last Jacobi ----
  // A: xj = hL@Q1 - i Q1
  gemm_t<32, 1, NN, 16><<<dim3(48 * 16), 256, 0, stream>>>(
      b0, NN, adjbf, NN, Vbuf, nullptr, nullptr, xjbuf, b1, dinv, h);
  // G1: y1 = xj + dinv*(xj - (hL@xj + i xj))
  gemm_t<32, 2, NN, 16><<<dim3(48 * 16), 256, 0, stream>>>(
      b1, NN, adjbf, NN, xjbuf, xjbuf, nullptr, ybuf, b2, dinv, h);
  // G2
  gemm_t<32, 2, NN, 16><<<dim3(48 * 16), 256, 0, stream>>>(
      b2, NN, adjbf, NN, xjbuf, ybuf, nullptr, ybuf, b1, dinv, h);
  // G3 + merge: W = y3 + Q0  (f32 -> xjbuf, bf16 -> b2)
  gemm_t<32, 3, NN, 16><<<dim3(48 * 16), 256, 0, stream>>>(
      b1, NN, adjbf, NN, xjbuf, ybuf, Q0f, xjbuf, b2, dinv, h);

  // ---- chain 2: csum = (G∘A)(W) ----
  // A: xj = hL@W - i W   (in-place xjbuf: element-aligned, safe)
  gemm_t<32, 1, NN, 16><<<dim3(48 * 16), 256, 0, stream>>>(
      b2, NN, adjbf, NN, xjbuf, nullptr, nullptr, xjbuf, b1, dinv, h);
  // G1
  gemm_t<32, 2, NN, 16><<<dim3(48 * 16), 256, 0, stream>>>(
      b1, NN, adjbf, NN, xjbuf, xjbuf, nullptr, ybuf, b2, dinv, h);
  // G2
  gemm_t<32, 2, NN, 16><<<dim3(48 * 16), 256, 0, stream>>>(
      b2, NN, adjbf, NN, xjbuf, ybuf, nullptr, ybuf, b1, dinv, h);
  // G3 -> final csum panel (bf16 out unused)
  gemm_t<32, 2, NN, 16><<<dim3(48 * 16), 256, 0, stream>>>(
      b1, NN, adjbf, NN, xjbuf, ybuf, nullptr, ybuf, b2, dinv, h);

  final_out<<<dim3(48, 4), 256, 0, stream>>>(Vbuf, ybuf, out);
}